// Round 2
// baseline (345.920 us; speedup 1.0000x reference)
//
#include <hip/hip_runtime.h>

#define DIM 1024
#define NH 16
#define HD 64
#define BATCH 16
#define SEQ 512
#define MROWS (BATCH*SEQ)   // 8192

using u16 = unsigned short;
typedef __attribute__((ext_vector_type(8))) u16 u16x8;
typedef __attribute__((ext_vector_type(4))) u16 u16x4;
typedef __attribute__((ext_vector_type(8))) __bf16 bf16x8;
typedef __attribute__((ext_vector_type(4))) float f32x4;
typedef __attribute__((ext_vector_type(4))) float float4v;

__device__ __forceinline__ float bf2f(u16 h) {
  unsigned u = ((unsigned)h) << 16;
  union { unsigned u; float f; } v; v.u = u; return v.f;
}
__device__ __forceinline__ u16 f2bf(float f) {
  union { float f; unsigned u; } v; v.f = f;
  unsigned u = v.u + 0x7fffu + ((v.u >> 16) & 1u);
  return (u16)(u >> 16);
}

// async global->LDS, 16B per lane. LDS dest must be wave-uniform-base + lane*16.
__device__ __forceinline__ void gld_lds16(const u16* g, u16* l) {
  __builtin_amdgcn_global_load_lds(
      (const __attribute__((address_space(1))) void*)g,
      (__attribute__((address_space(3))) void*)l, 16, 0, 0);
}

__device__ __forceinline__ f32x4 mfma16(u16x8 a, u16x8 b, f32x4 c) {
  return __builtin_amdgcn_mfma_f32_16x16x32_bf16(
      __builtin_bit_cast(bf16x8, a), __builtin_bit_cast(bf16x8, b), c, 0, 0, 0);
}

// ---------------- fp32 -> bf16 conversion ----------------
__global__ void f32_to_bf16_kernel(const float* __restrict__ in, u16* __restrict__ out, int n) {
  int i = (blockIdx.x * blockDim.x + threadIdx.x) * 4;
  if (i >= n) return;
  float4v v = *(const float4v*)(in + i);
  u16x4 o;
  o.x = f2bf(v.x); o.y = f2bf(v.y); o.z = f2bf(v.z); o.w = f2bf(v.w);
  *(u16x4*)(out + i) = o;
}

// ---------------- RoPE tables: [SEQ][32] cos/sin ----------------
__global__ void rope_tables_kernel(float* __restrict__ ctab, float* __restrict__ stab) {
  int t = blockIdx.x * blockDim.x + threadIdx.x;  // SEQ*32
  int s = t >> 5, j = t & 31;
  float invf = powf(10000.f, -(float)j / 32.f);
  float a = (float)s * invf;
  ctab[t] = cosf(a);
  stab[t] = sinf(a);
}

// ---------------- RoPE applied in-place to q and k (bf16) ----------------
__global__ void rope_kernel(u16* __restrict__ Q, u16* __restrict__ K,
                            const float* __restrict__ ctab, const float* __restrict__ stab) {
  int t = blockIdx.x * blockDim.x + threadIdx.x;  // 524288 per tensor
  u16* X = blockIdx.z ? K : Q;
  int j = t & 3;            // 8-group within the 32 lower dims
  int h = (t >> 2) & 15;
  int m = t >> 6;           // row 0..8191
  int s = m & (SEQ - 1);
  u16* base = X + (size_t)m * DIM + h * HD + j * 8;
  u16x8 lo = *(u16x8*)base;
  u16x8 hi = *(u16x8*)(base + 32);
  const float* cp = ctab + s * 32 + j * 8;
  const float* sp = stab + s * 32 + j * 8;
  u16x8 lo2, hi2;
#pragma unroll
  for (int i = 0; i < 8; i++) {
    float c = cp[i], sn = sp[i];
    float xl = bf2f(lo[i]), xh = bf2f(hi[i]);
    lo2[i] = f2bf(xl * c - xh * sn);
    hi2[i] = f2bf(xh * c + xl * sn);
  }
  *(u16x8*)base = lo2;
  *(u16x8*)(base + 32) = hi2;
}

// ---------------- GEMM: C[m][n] = sum_k A[m][k] * B[n][k]  (B given transposed) --------
// m97 structure: 128x128 tile, BK=32, 4 waves (2x2), 16x16x32 MFMA, global_load_lds.
#define BM 128
#define BN 128
#define BK 32

template <typename CT>
__global__ __launch_bounds__(256) void gemm_bt(const u16* __restrict__ A,
                                               const u16* __restrict__ B,
                                               CT* __restrict__ C, int M, int N, int K) {
  __shared__ alignas(16) u16 As[BM * BK];
  __shared__ alignas(16) u16 Bs[BN * BK];
  const int m0 = blockIdx.y * BM, n0 = blockIdx.x * BN;
  const int tid = threadIdx.x, lane = tid & 63;
  const int w = tid >> 6, wr = w >> 1, wc = w & 1;
  const int lr = lane & 15, kgrp = lane >> 4, koff = kgrp * 8;

  f32x4 acc[4][4] = {};

  for (int kt = 0; kt < K; kt += BK) {
#pragma unroll
    for (int i = 0; i < 2; i++) {
      int c = tid + i * 256;          // 512 16B chunks per tile
      int r_ = c >> 2, seg = c & 3;
      gld_lds16(A + (size_t)(m0 + r_) * K + kt + seg * 8, &As[c * 8]);
      gld_lds16(B + (size_t)(n0 + r_) * K + kt + seg * 8, &Bs[c * 8]);
    }
    __syncthreads();
    u16x8 a[4], b[4];
#pragma unroll
    for (int i = 0; i < 4; i++)
      a[i] = *(const u16x8*)(&As[(wr * 64 + i * 16 + lr) * BK + koff]);
#pragma unroll
    for (int j = 0; j < 4; j++)
      b[j] = *(const u16x8*)(&Bs[(wc * 64 + j * 16 + lr) * BK + koff]);
#pragma unroll
    for (int i = 0; i < 4; i++)
#pragma unroll
      for (int j = 0; j < 4; j++)
        acc[i][j] = mfma16(a[i], b[j], acc[i][j]);
    __syncthreads();
  }

#pragma unroll
  for (int i = 0; i < 4; i++) {
    int grow = m0 + wr * 64 + i * 16 + kgrp * 4;
#pragma unroll
    for (int j = 0; j < 4; j++) {
      int gcol = n0 + wc * 64 + j * 16 + lr;
#pragma unroll
      for (int r = 0; r < 4; r++) {
        float v = acc[i][j][r];
        size_t idx = (size_t)(grow + r) * N + gcol;
        if constexpr (sizeof(CT) == 2) C[idx] = f2bf(v);
        else C[idx] = v;
      }
    }
  }
}

// ---------------- Flash attention (causal), bf16 in/out, fp32 softmax ----------------
// grid: (S/64, B*H). Block: 256 threads = 4 waves; wave w owns q rows [w*16, w*16+16).
__global__ __launch_bounds__(256) void attn_kernel(const u16* __restrict__ Q,
                                                   const u16* __restrict__ K,
                                                   const u16* __restrict__ V,
                                                   u16* __restrict__ O) {
  __shared__ alignas(16) u16 Ks[64 * 64];   // K tile   [kv][d]
  __shared__ alignas(16) u16 Vs[64 * 64];   // V tile   [kv][d]
  __shared__ alignas(16) u16 Vt[64 * 72];   // V^T tile [d][kv], padded stride 72
  __shared__ alignas(16) u16 Ps[4][16 * 64];// per-wave P tile [q][kv]

  const int qt = blockIdx.x, bh = blockIdx.y;
  const int b = bh >> 4, h = bh & 15;
  const int tid = threadIdx.x, lane = tid & 63, w = tid >> 6;
  const int lr = lane & 15, kgrp = lane >> 4, koff = kgrp * 8;

  const int q0 = qt * 64;

  // Q fragments, held in registers the whole kernel
  const u16* qptr = Q + ((size_t)(b * SEQ + q0 + w * 16 + lr)) * DIM + h * HD;
  u16x8 qf0 = *(const u16x8*)(qptr + koff);
  u16x8 qf1 = *(const u16x8*)(qptr + 32 + koff);

  f32x4 acc[4] = {};                 // O accum: row=(kgrp*4+r) q, col=j*16+lr d
  float mrow[4], lrow[4];
#pragma unroll
  for (int r = 0; r < 4; r++) { mrow[r] = -INFINITY; lrow[r] = 0.f; }

  const float scale = 0.125f;        // 1/sqrt(64)

  for (int kt = 0; kt <= qt; ++kt) {
    const u16* Kg = K + ((size_t)(b * SEQ + kt * 64)) * DIM + h * HD;
    const u16* Vg = V + ((size_t)(b * SEQ + kt * 64)) * DIM + h * HD;
#pragma unroll
    for (int i = 0; i < 2; i++) {
      int c = tid + i * 256;         // 512 chunks of 16B each
      int r_ = c >> 3, seg = c & 7;
      gld_lds16(Kg + (size_t)r_ * DIM + seg * 8, &Ks[c * 8]);
      gld_lds16(Vg + (size_t)r_ * DIM + seg * 8, &Vs[c * 8]);
    }
    __syncthreads();   // staging complete (barrier drains vmcnt)

    // transpose V tile into Vt[d][kv]
#pragma unroll
    for (int i = 0; i < 2; i++) {
      int c = tid + i * 256;
      int r_ = c >> 3, seg = c & 7;
      u16x8 vv = *(const u16x8*)(&Vs[r_ * 64 + seg * 8]);
#pragma unroll
      for (int jj = 0; jj < 8; jj++) Vt[(seg * 8 + jj) * 72 + r_] = vv[jj];
    }

    // S = Q K^T for this wave's 16 q-rows x 64 kv
    f32x4 sacc[4] = {};
#pragma unroll
    for (int j = 0; j < 4; j++) {
      u16x8 kf0 = *(const u16x8*)(&Ks[(j * 16 + lr) * 64 + koff]);
      u16x8 kf1 = *(const u16x8*)(&Ks[(j * 16 + lr) * 64 + 32 + koff]);
      sacc[j] = mfma16(qf0, kf0, sacc[j]);
      sacc[j] = mfma16(qf1, kf1, sacc[j]);
    }

    // scale + causal mask
    float sv[4][4];
#pragma unroll
    for (int j = 0; j < 4; j++)
#pragma unroll
      for (int r = 0; r < 4; r++) {
        float s = sacc[j][r] * scale;
        int kv = kt * 64 + j * 16 + lr;
        int qg = q0 + w * 16 + kgrp * 4 + r;
        if (kv > qg) s = -1e30f;
        sv[j][r] = s;
      }

    // online softmax: row stats via 16-lane-group butterfly
    float pr[4][4];
#pragma unroll
    for (int r = 0; r < 4; r++) {
      float mx = fmaxf(fmaxf(sv[0][r], sv[1][r]), fmaxf(sv[2][r], sv[3][r]));
#pragma unroll
      for (int off = 1; off < 16; off <<= 1) mx = fmaxf(mx, __shfl_xor(mx, off, 64));
      float mnew = fmaxf(mrow[r], mx);
      float f = __expf(mrow[r] - mnew);   // -inf initial -> 0
      mrow[r] = mnew;
      lrow[r] *= f;
#pragma unroll
      for (int j = 0; j < 4; j++) acc[j][r] *= f;
      float s0 = 0.f;
#pragma unroll
      for (int j = 0; j < 4; j++) { float p = __expf(sv[j][r] - mnew); pr[j][r] = p; s0 += p; }
#pragma unroll
      for (int off = 1; off < 16; off <<= 1) s0 += __shfl_xor(s0, off, 64);
      lrow[r] += s0;
    }

    // write P (bf16) to per-wave LDS to re-layout S-frag -> A-frag
#pragma unroll
    for (int j = 0; j < 4; j++)
#pragma unroll
      for (int r = 0; r < 4; r++)
        Ps[w][(kgrp * 4 + r) * 64 + j * 16 + lr] = f2bf(pr[j][r]);

    __syncthreads();   // Vt visible to all; Ps drained (wave-local anyway)

    // PV: O += P (16 x 64) * V (64 x 64)
#pragma unroll
    for (int ks = 0; ks < 2; ++ks) {
      u16x8 pa = *(const u16x8*)(&Ps[w][lr * 64 + ks * 32 + koff]);
#pragma unroll
      for (int j = 0; j < 4; j++) {
        u16x8 vb = *(const u16x8*)(&Vt[(j * 16 + lr) * 72 + ks * 32 + koff]);
        acc[j] = mfma16(pa, vb, acc[j]);
      }
    }
  }

  // normalize + store (B,S,D) layout at [b*S + q][h*64 + d]
  const size_t rowbase = (size_t)(b * SEQ + q0 + w * 16);
#pragma unroll
  for (int r = 0; r < 4; r++) {
    float inv = 1.f / lrow[r];
    u16* op = O + (rowbase + kgrp * 4 + r) * DIM + h * HD;
#pragma unroll
    for (int j = 0; j < 4; j++) op[j * 16 + lr] = f2bf(acc[j][r] * inv);
  }
}

// ---------------- host launcher ----------------
extern "C" void kernel_launch(void* const* d_in, const int* in_sizes, int n_in,
                              void* d_out, int out_size, void* d_ws, size_t ws_size,
                              hipStream_t stream) {
  const float* x  = (const float*)d_in[0];
  const float* Wq = (const float*)d_in[1];
  const float* Wk = (const float*)d_in[2];
  const float* Wv = (const float*)d_in[3];
  const float* Wo = (const float*)d_in[4];
  float* out = (float*)d_out;

  char* ws = (char*)d_ws;
  u16* xb    = (u16*)(ws);                       // 16.78 MB
  u16* qb    = (u16*)(ws + 16777216);
  u16* kb    = (u16*)(ws + 33554432);
  u16* vb    = (u16*)(ws + 50331648);
  u16* attnb = (u16*)(ws + 67108864);
  u16* wqb   = (u16*)(ws + 83886080);
  u16* wkb   = (u16*)(ws + 85983232);
  u16* wvb   = (u16*)(ws + 88080384);
  u16* wob   = (u16*)(ws + 90177536);
  float* ctab = (float*)(ws + 92274688);
  float* stab = (float*)(ws + 92340224);

  const int nx = MROWS * DIM;        // 8388608
  const int nw = DIM * DIM;          // 1048576

  f32_to_bf16_kernel<<<nx / 4 / 256, 256, 0, stream>>>(x, xb, nx);
  f32_to_bf16_kernel<<<nw / 4 / 256, 256, 0, stream>>>(Wq, wqb, nw);
  f32_to_bf16_kernel<<<nw / 4 / 256, 256, 0, stream>>>(Wk, wkb, nw);
  f32_to_bf16_kernel<<<nw / 4 / 256, 256, 0, stream>>>(Wv, wvb, nw);
  f32_to_bf16_kernel<<<nw / 4 / 256, 256, 0, stream>>>(Wo, wob, nw);
  rope_tables_kernel<<<SEQ * 32 / 256, 256, 0, stream>>>(ctab, stab);

  dim3 gg(DIM / BN, MROWS / BM);     // (8, 64)
  gemm_bt<u16><<<gg, 256, 0, stream>>>(xb, wqb, qb, MROWS, DIM, DIM);
  gemm_bt<u16><<<gg, 256, 0, stream>>>(xb, wkb, kb, MROWS, DIM, DIM);
  gemm_bt<u16><<<gg, 256, 0, stream>>>(xb, wvb, vb, MROWS, DIM, DIM);

  rope_kernel<<<dim3(MROWS * NH * 4 / 256, 1, 2), 256, 0, stream>>>(qb, kb, ctab, stab);

  attn_kernel<<<dim3(SEQ / 64, BATCH * NH), 256, 0, stream>>>(qb, kb, vb, attnb);

  gemm_bt<float><<<gg, 256, 0, stream>>>(attnb, wob, out, MROWS, DIM, DIM);
}

// Round 4
// 319.366 us; speedup vs baseline: 1.0831x; 1.0831x over previous
//
#include <hip/hip_runtime.h>

#define DIM 1024
#define NH 16
#define HD 64
#define BATCH 16
#define SEQ 512
#define MROWS (BATCH*SEQ)   // 8192

using u16 = unsigned short;
using u32 = unsigned int;
typedef __attribute__((ext_vector_type(8))) u16 u16x8;
typedef __attribute__((ext_vector_type(4))) u16 u16x4;
typedef __attribute__((ext_vector_type(8))) __bf16 bf16x8;
typedef __attribute__((ext_vector_type(4))) float f32x4;
typedef __attribute__((ext_vector_type(4))) float float4v;

__device__ __forceinline__ float bf2f(u16 h) {
  unsigned u = ((unsigned)h) << 16;
  union { unsigned u; float f; } v; v.u = u; return v.f;
}
__device__ __forceinline__ u16 f2bf(float f) {
  union { float f; unsigned u; } v; v.f = f;
  unsigned u = v.u + 0x7fffu + ((v.u >> 16) & 1u);
  return (u16)(u >> 16);
}
// granule swizzle for 64-u16 rows (8 granules of 16B): spreads column reads/writes
__device__ __forceinline__ int swz(int r) { return (r & 7) ^ (r >> 3); }

// async global->LDS, 16B per lane. LDS dest must be wave-uniform base + lane*16.
__device__ __forceinline__ void gld_lds16(const u16* g, u16* l) {
  __builtin_amdgcn_global_load_lds(
      (const __attribute__((address_space(1))) void*)g,
      (__attribute__((address_space(3))) void*)l, 16, 0, 0);
}

__device__ __forceinline__ f32x4 mfma16(u16x8 a, u16x8 b, f32x4 c) {
  return __builtin_amdgcn_mfma_f32_16x16x32_bf16(
      __builtin_bit_cast(bf16x8, a), __builtin_bit_cast(bf16x8, b), c, 0, 0, 0);
}

// ---------------- fp32 -> bf16 conversion ----------------
__global__ void f32_to_bf16_kernel(const float* __restrict__ in, u16* __restrict__ out, int n) {
  int i = (blockIdx.x * blockDim.x + threadIdx.x) * 4;
  if (i >= n) return;
  float4v v = *(const float4v*)(in + i);
  u16x4 o;
  o.x = f2bf(v.x); o.y = f2bf(v.y); o.z = f2bf(v.z); o.w = f2bf(v.w);
  *(u16x4*)(out + i) = o;
}

// ---------------- RoPE tables: [SEQ][32] cos/sin ----------------
__global__ void rope_tables_kernel(float* __restrict__ ctab, float* __restrict__ stab) {
  int t = blockIdx.x * blockDim.x + threadIdx.x;  // SEQ*32
  int s = t >> 5, j = t & 31;
  float invf = powf(10000.f, -(float)j / 32.f);
  float a = (float)s * invf;
  ctab[t] = cosf(a);
  stab[t] = sinf(a);
}

// ---------------- RoPE applied in-place to q and k (bf16) ----------------
__global__ void rope_kernel(u16* __restrict__ Q, u16* __restrict__ K,
                            const float* __restrict__ ctab, const float* __restrict__ stab) {
  int t = blockIdx.x * blockDim.x + threadIdx.x;  // 524288 per tensor
  u16* X = blockIdx.z ? K : Q;
  int j = t & 3;            // 8-group within the 32 lower dims
  int h = (t >> 2) & 15;
  int m = t >> 6;           // row 0..8191
  int s = m & (SEQ - 1);
  u16* base = X + (size_t)m * DIM + h * HD + j * 8;
  u16x8 lo = *(u16x8*)base;
  u16x8 hi = *(u16x8*)(base + 32);
  const float* cp = ctab + s * 32 + j * 8;
  const float* sp = stab + s * 32 + j * 8;
  u16x8 lo2, hi2;
#pragma unroll
  for (int i = 0; i < 8; i++) {
    float c = cp[i], sn = sp[i];
    float xl = bf2f(lo[i]), xh = bf2f(hi[i]);
    lo2[i] = f2bf(xl * c - xh * sn);
    hi2[i] = f2bf(xh * c + xl * sn);
  }
  *(u16x8*)base = lo2;
  *(u16x8*)(base + 32) = hi2;
}

// ---------------- GEMM 128x128 tile, BK=32, m97 structure ----------------
#define BM 128
#define BN 128
#define BK 32

// fused QKV: B = concatenated [3072][1024] weights; output split by column block
__global__ __launch_bounds__(256) void gemm_qkv(const u16* __restrict__ A,
                                                const u16* __restrict__ Bw,
                                                u16* __restrict__ Cq, u16* __restrict__ Ck,
                                                u16* __restrict__ Cv) {
  __shared__ alignas(16) u16 As[BM * BK];
  __shared__ alignas(16) u16 Bs[BN * BK];
  const int K = DIM, N = DIM;
  const int m0 = blockIdx.y * BM;
  const int n0g = blockIdx.x * BN;                 // 0..3071
  u16* C = (n0g < 1024) ? Cq : (n0g < 2048) ? Ck : Cv;
  const int n0 = n0g & 1023;
  const int tid = threadIdx.x, lane = tid & 63;
  const int w = tid >> 6, wr = w >> 1, wc = w & 1;
  const int lr = lane & 15, kgrp = lane >> 4, koff = kgrp * 8;

  f32x4 acc[4][4] = {};

  for (int kt = 0; kt < K; kt += BK) {
#pragma unroll
    for (int i = 0; i < 2; i++) {
      int c = tid + i * 256;
      int r_ = c >> 2, seg = c & 3;
      gld_lds16(A + (size_t)(m0 + r_) * K + kt + seg * 8, &As[c * 8]);
      gld_lds16(Bw + (size_t)(n0g + r_) * K + kt + seg * 8, &Bs[c * 8]);
    }
    __syncthreads();
    u16x8 a[4], b[4];
#pragma unroll
    for (int i = 0; i < 4; i++)
      a[i] = *(const u16x8*)(&As[(wr * 64 + i * 16 + lr) * BK + koff]);
#pragma unroll
    for (int j = 0; j < 4; j++)
      b[j] = *(const u16x8*)(&Bs[(wc * 64 + j * 16 + lr) * BK + koff]);
#pragma unroll
    for (int i = 0; i < 4; i++)
#pragma unroll
      for (int j = 0; j < 4; j++)
        acc[i][j] = mfma16(a[i], b[j], acc[i][j]);
    __syncthreads();
  }

#pragma unroll
  for (int i = 0; i < 4; i++) {
    int grow = m0 + wr * 64 + i * 16 + kgrp * 4;
#pragma unroll
    for (int j = 0; j < 4; j++) {
      int gcol = n0 + wc * 64 + j * 16 + lr;
#pragma unroll
      for (int r = 0; r < 4; r++)
        C[(size_t)(grow + r) * N + gcol] = f2bf(acc[i][j][r]);
    }
  }
}

template <typename CT>
__global__ __launch_bounds__(256) void gemm_bt(const u16* __restrict__ A,
                                               const u16* __restrict__ B,
                                               CT* __restrict__ C, int M, int N, int K) {
  __shared__ alignas(16) u16 As[BM * BK];
  __shared__ alignas(16) u16 Bs[BN * BK];
  const int m0 = blockIdx.y * BM, n0 = blockIdx.x * BN;
  const int tid = threadIdx.x, lane = tid & 63;
  const int w = tid >> 6, wr = w >> 1, wc = w & 1;
  const int lr = lane & 15, kgrp = lane >> 4, koff = kgrp * 8;

  f32x4 acc[4][4] = {};

  for (int kt = 0; kt < K; kt += BK) {
#pragma unroll
    for (int i = 0; i < 2; i++) {
      int c = tid + i * 256;
      int r_ = c >> 2, seg = c & 3;
      gld_lds16(A + (size_t)(m0 + r_) * K + kt + seg * 8, &As[c * 8]);
      gld_lds16(B + (size_t)(n0 + r_) * K + kt + seg * 8, &Bs[c * 8]);
    }
    __syncthreads();
    u16x8 a[4], b[4];
#pragma unroll
    for (int i = 0; i < 4; i++)
      a[i] = *(const u16x8*)(&As[(wr * 64 + i * 16 + lr) * BK + koff]);
#pragma unroll
    for (int j = 0; j < 4; j++)
      b[j] = *(const u16x8*)(&Bs[(wc * 64 + j * 16 + lr) * BK + koff]);
#pragma unroll
    for (int i = 0; i < 4; i++)
#pragma unroll
      for (int j = 0; j < 4; j++)
        acc[i][j] = mfma16(a[i], b[j], acc[i][j]);
    __syncthreads();
  }

#pragma unroll
  for (int i = 0; i < 4; i++) {
    int grow = m0 + wr * 64 + i * 16 + kgrp * 4;
#pragma unroll
    for (int j = 0; j < 4; j++) {
      int gcol = n0 + wc * 64 + j * 16 + lr;
#pragma unroll
      for (int r = 0; r < 4; r++) {
        float v = acc[i][j][r];
        size_t idx = (size_t)(grow + r) * N + gcol;
        if constexpr (sizeof(CT) == 2) C[idx] = f2bf(v);
        else C[idx] = v;
      }
    }
  }
}

// ---------------- Flash attention v2 (causal), swizzled LDS ----------------
// grid: (S/64, B*H). Block: 256 threads = 4 waves; wave w owns q rows [w*16, w*16+16).
// Ks: [64][64] u16, granule-swizzled (source-preswizzled global_load_lds).
// Vt: [64][64] u16 = V^T, granule-swizzled, built by reg-staged packed transpose.
// Ps: per-wave [16][64] u16, granule-swizzled.
__global__ __launch_bounds__(256) void attn_kernel(const u16* __restrict__ Q,
                                                   const u16* __restrict__ K,
                                                   const u16* __restrict__ V,
                                                   u16* __restrict__ O) {
  __shared__ alignas(16) u16 Ks[64 * 64];
  __shared__ alignas(16) u16 Vt[64 * 64];
  __shared__ alignas(16) u16 Ps[4][16 * 64];

  const int qt = blockIdx.x, bh = blockIdx.y;
  const int b = bh >> 4, h = bh & 15;
  const int tid = threadIdx.x, lane = tid & 63, w = tid >> 6;
  const int lr = lane & 15, kgrp = lane >> 4, koff = kgrp * 8;
  const int q0 = qt * 64;

  // V-transpose work assignment: one 2-row x 8-col micro tile per thread
  const int va = tid >> 3;          // kv-pair index 0..31
  const int vd = tid & 7;           // d segment 0..7

  // Q fragments, held in registers the whole kernel
  const u16* qptr = Q + ((size_t)(b * SEQ + q0 + w * 16 + lr)) * DIM + h * HD;
  u16x8 qf0 = *(const u16x8*)(qptr + koff);
  u16x8 qf1 = *(const u16x8*)(qptr + 32 + koff);

  f32x4 acc[4] = {};                 // O accum: row=(kgrp*4+r) q, col=j*16+lr d
  float mrow[4], lrow[4];
#pragma unroll
  for (int r = 0; r < 4; r++) { mrow[r] = -INFINITY; lrow[r] = 0.f; }

  const float scale = 0.125f;        // 1/sqrt(64)
  u32* Vt32 = (u32*)Vt;

  for (int kt = 0; kt <= qt; ++kt) {
    const u16* Kg = K + ((size_t)(b * SEQ + kt * 64)) * DIM + h * HD;
    const u16* Vg = V + ((size_t)(b * SEQ + kt * 64)) * DIM + h * HD;

    // V rows (reg-staged) — issue first so Vt writes only need vmcnt(2)
    u16x8 v0 = *(const u16x8*)(Vg + (size_t)(2 * va) * DIM + vd * 8);
    u16x8 v1 = *(const u16x8*)(Vg + (size_t)(2 * va + 1) * DIM + vd * 8);

    // K staging: linear LDS dest, pre-swizzled global source granule
#pragma unroll
    for (int i = 0; i < 2; i++) {
      int c = tid + i * 256;         // 512 chunks of 16B
      int r_ = c >> 3, p = c & 7;
      int ck = p ^ swz(r_);
      gld_lds16(Kg + (size_t)r_ * DIM + ck * 8, &Ks[c * 8]);
    }

    // packed transposed V writes: Vt[d][kv], u32 = (kv even | kv odd << 16)
#pragma unroll
    for (int i = 0; i < 8; i++) {
      int d = vd * 8 + i;
      u32 val = (u32)v0[i] | ((u32)v1[i] << 16);
      Vt32[d * 32 + (((va >> 2) ^ swz(d)) << 2) + (va & 3)] = val;
    }

    __syncthreads();   // K arrived (vmcnt drain), Vt visible to all waves

    // S = Q K^T for this wave's 16 q-rows x 64 kv
    f32x4 sacc[4] = {};
#pragma unroll
    for (int j = 0; j < 4; j++) {
      int row = j * 16 + lr;
      int p0 = kgrp ^ swz(row);
      u16x8 kf0 = *(const u16x8*)(&Ks[row * 64 + p0 * 8]);
      u16x8 kf1 = *(const u16x8*)(&Ks[row * 64 + (p0 ^ 4) * 8]);
      sacc[j] = mfma16(qf0, kf0, sacc[j]);
      sacc[j] = mfma16(qf1, kf1, sacc[j]);
    }

    // scale + causal mask (diagonal tile only)
    float sv[4][4];
    if (kt == qt) {
#pragma unroll
      for (int j = 0; j < 4; j++)
#pragma unroll
        for (int r = 0; r < 4; r++) {
          float s = sacc[j][r] * scale;
          if (j * 16 + lr > w * 16 + kgrp * 4 + r) s = -1e30f;
          sv[j][r] = s;
        }
    } else {
#pragma unroll
      for (int j = 0; j < 4; j++)
#pragma unroll
        for (int r = 0; r < 4; r++) sv[j][r] = sacc[j][r] * scale;
    }

    // online softmax: row stats via 16-lane-group butterfly
    float pr[4][4];
#pragma unroll
    for (int r = 0; r < 4; r++) {
      float mx = fmaxf(fmaxf(sv[0][r], sv[1][r]), fmaxf(sv[2][r], sv[3][r]));
#pragma unroll
      for (int off = 1; off < 16; off <<= 1) mx = fmaxf(mx, __shfl_xor(mx, off, 64));
      float mnew = fmaxf(mrow[r], mx);
      float f = __expf(mrow[r] - mnew);   // -inf initial -> 0
      mrow[r] = mnew;
      lrow[r] *= f;
#pragma unroll
      for (int j = 0; j < 4; j++) acc[j][r] *= f;
      float s0 = 0.f;
#pragma unroll
      for (int j = 0; j < 4; j++) { float p = __expf(sv[j][r] - mnew); pr[j][r] = p; s0 += p; }
#pragma unroll
      for (int off = 1; off < 16; off <<= 1) s0 += __shfl_xor(s0, off, 64);
      lrow[r] += s0;
    }

    // write P (bf16) to per-wave swizzled LDS: S-frag -> A-frag relayout
#pragma unroll
    for (int j = 0; j < 4; j++) {
      int gk = 2 * j + (lr >> 3);
#pragma unroll
      for (int r = 0; r < 4; r++) {
        int q = kgrp * 4 + r;
        Ps[w][q * 64 + ((gk ^ swz(q)) << 3) + (lr & 7)] = f2bf(pr[j][r]);
      }
    }

    // PV: O += P (16 x 64) * V (64 x 64)   (wave-local Ps, compiler orders lgkmcnt)
#pragma unroll
    for (int ks = 0; ks < 2; ++ks) {
      int g = ks * 4 + kgrp;
      u16x8 pa = *(const u16x8*)(&Ps[w][lr * 64 + ((g ^ swz(lr)) << 3)]);
#pragma unroll
      for (int j = 0; j < 4; j++) {
        int d = j * 16 + lr;
        u16x8 vb = *(const u16x8*)(&Vt[d * 64 + ((g ^ swz(d)) << 3)]);
        acc[j] = mfma16(pa, vb, acc[j]);
      }
    }
    __syncthreads();   // protect Ks/Vt before next tile's staging
  }

  // normalize + store (B,S,D) layout at [b*S + q][h*64 + d]
  const size_t rowbase = (size_t)(b * SEQ + q0 + w * 16);
#pragma unroll
  for (int r = 0; r < 4; r++) {
    float inv = 1.f / lrow[r];
    u16* op = O + (rowbase + kgrp * 4 + r) * DIM + h * HD;
#pragma unroll
    for (int j = 0; j < 4; j++) op[j * 16 + lr] = f2bf(acc[j][r] * inv);
  }
}

// ---------------- host launcher ----------------
extern "C" void kernel_launch(void* const* d_in, const int* in_sizes, int n_in,
                              void* d_out, int out_size, void* d_ws, size_t ws_size,
                              hipStream_t stream) {
  const float* x  = (const float*)d_in[0];
  const float* Wq = (const float*)d_in[1];
  const float* Wk = (const float*)d_in[2];
  const float* Wv = (const float*)d_in[3];
  const float* Wo = (const float*)d_in[4];
  float* out = (float*)d_out;

  char* ws = (char*)d_ws;
  u16* xb    = (u16*)(ws);                       // 16.78 MB
  u16* qb    = (u16*)(ws + 16777216);
  u16* kb    = (u16*)(ws + 33554432);
  u16* vb    = (u16*)(ws + 50331648);
  u16* attnb = (u16*)(ws + 67108864);
  u16* wqb   = (u16*)(ws + 83886080);            // wq,wk,wv contiguous = [3072][1024]
  u16* wkb   = (u16*)(ws + 85983232);
  u16* wvb   = (u16*)(ws + 88080384);
  u16* wob   = (u16*)(ws + 90177536);
  float* ctab = (float*)(ws + 92274688);
  float* stab = (float*)(ws + 92340224);

  const int nx = MROWS * DIM;        // 8388608
  const int nw = DIM * DIM;          // 1048576

  f32_to_bf16_kernel<<<nx / 4 / 256, 256, 0, stream>>>(x, xb, nx);
  f32_to_bf16_kernel<<<nw / 4 / 256, 256, 0, stream>>>(Wq, wqb, nw);
  f32_to_bf16_kernel<<<nw / 4 / 256, 256, 0, stream>>>(Wk, wkb, nw);
  f32_to_bf16_kernel<<<nw / 4 / 256, 256, 0, stream>>>(Wv, wvb, nw);
  f32_to_bf16_kernel<<<nw / 4 / 256, 256, 0, stream>>>(Wo, wob, nw);
  rope_tables_kernel<<<SEQ * 32 / 256, 256, 0, stream>>>(ctab, stab);

  // fused QKV projection: [8192][1024] x [3072][1024]^T
  gemm_qkv<<<dim3(3 * DIM / BN, MROWS / BM), 256, 0, stream>>>(xb, wqb, qb, kb, vb);

  rope_kernel<<<dim3(MROWS * NH * 4 / 256, 1, 2), 256, 0, stream>>>(qb, kb, ctab, stab);

  attn_kernel<<<dim3(SEQ / 64, BATCH * NH), 256, 0, stream>>>(qb, kb, vb, attnb);

  gemm_bt<float><<<dim3(DIM / BN, MROWS / BM), 256, 0, stream>>>(attnb, wob, out, MROWS, DIM, DIM);
}